// Round 1
// baseline (837.356 us; speedup 1.0000x reference)
//
#include <hip/hip_runtime.h>
#include <hip/hip_bf16.h>

#define N_NODESC 50000
#define N_EDGESC 1600000
#define SDIM 64
#define VDIM 32
#define HID 96
#define IN_DIMC 163

typedef float f32x4 __attribute__((ext_vector_type(4)));
typedef short s16x8 __attribute__((ext_vector_type(8)));

__device__ __forceinline__ float bf2f(__hip_bfloat16 x) { return __bfloat162float(x); }
__device__ __forceinline__ __hip_bfloat16 f2bf(float x) { return __float2bfloat16(x); }

// ---------------------------------------------------------------------------
// Detect whether edge_index arrived as int64 (odd int32 words all zero) or int32.
__global__ void detect_kernel(const int* ei, int* flag) {
    if (blockIdx.x == 0 && threadIdx.x == 0) {
        int z = 1;
        for (int k = 0; k < 64; ++k) {
            if (ei[2 * k + 1] != 0) { z = 0; break; }
        }
        *flag = z;  // 1 -> int64 layout
    }
}

// ---------------------------------------------------------------------------
// Init out with the residual (h_scalar | h_vector); atomics accumulate on top.
__global__ void init_out(const float* __restrict__ hs, const float* __restrict__ hv,
                         float* __restrict__ out) {
    int i = blockIdx.x * blockDim.x + threadIdx.x;
    if (i >= N_NODESC * (SDIM + VDIM)) return;
    out[i] = (i < N_NODESC * SDIM) ? hs[i] : hv[i - N_NODESC * SDIM];
}

// ---------------------------------------------------------------------------
// Per-node tables: Pp = hs@W1[0:64] + b1, Q = hs@W1[64:128],
// U = hv@W1c, V = hv@W1c' (pair-swapped, sign-flipped). bf16 storage.
__global__ __launch_bounds__(128) void node_precompute(
    const float* __restrict__ hs, const float* __restrict__ hv,
    const float* __restrict__ W1, const float* __restrict__ b1,
    __hip_bfloat16* __restrict__ Pp, __hip_bfloat16* __restrict__ Qt,
    __hip_bfloat16* __restrict__ Ut, __hip_bfloat16* __restrict__ Vt) {
    int n = blockIdx.x;
    __shared__ float s_hs[SDIM];
    __shared__ float s_hv[VDIM];
    int t = threadIdx.x;
    if (t < 64) s_hs[t] = hs[n * SDIM + t];
    else if (t < 96) s_hv[t - 64] = hv[n * VDIM + (t - 64)];
    __syncthreads();
    if (t < HID) {
        float p = b1[t], q = 0.f, u = 0.f, v = 0.f;
        for (int k = 0; k < 64; ++k) {
            float x = s_hs[k];
            p += x * W1[k * HID + t];
            q += x * W1[(64 + k) * HID + t];
        }
        for (int pr = 0; pr < 16; ++pr) {
            float x = s_hv[2 * pr], y = s_hv[2 * pr + 1];
            float wa = W1[(128 + 2 * pr) * HID + t];
            float wb = W1[(128 + 2 * pr + 1) * HID + t];
            u += x * wa + y * wb;
            v += x * wb - y * wa;
        }
        Pp[n * HID + t] = f2bf(p);
        Qt[n * HID + t] = f2bf(q);
        Ut[n * HID + t] = f2bf(u);
        Vt[n * HID + t] = f2bf(v);
    }
}

// ---------------------------------------------------------------------------
// Main edge kernel: 64 edges/tile per block; layer1 via table combine (VALU),
// layer2 via mfma_f32_16x16x32_bf16 with W2 fragments resident in VGPRs.
__global__ __launch_bounds__(256) void edge_kernel(
    const int* __restrict__ ei, const float* __restrict__ pos,
    const float* __restrict__ ori, const float* __restrict__ W1,
    const float* __restrict__ W2, const float* __restrict__ b2,
    const __hip_bfloat16* __restrict__ Pp, const __hip_bfloat16* __restrict__ Qt,
    const __hip_bfloat16* __restrict__ Ut, const __hip_bfloat16* __restrict__ Vt,
    const int* __restrict__ flag64, float* __restrict__ out) {
    __shared__ int s_src[64], s_dst[64];
    __shared__ float s_c[64], s_s[64], s_d[64], s_cg[64], s_sg[64];
    __shared__ float s_w1d[3][HID];
    __shared__ __hip_bfloat16 hA[64][104];    // A tiles, row pitch 104 (bank stagger)
    __shared__ __hip_bfloat16 W2T[HID][104];  // W2 transposed: W2T[n][k]

    const int t = threadIdx.x;
    const int lane = t & 63;
    const int w = t >> 6;        // wave id 0..3
    const int m16 = lane & 15;
    const int q = lane >> 4;

    // Stage W2^T (coalesced global read; one-time per block)
    for (int idx = t; idx < HID * HID; idx += 256) {
        int k = idx / HID;
        int n = idx - k * HID;
        W2T[n][k] = f2bf(W2[idx]);  // W2 flat = k*96+n = idx
    }
    // Stage geo weight rows 160..162
    for (int idx = t; idx < 3 * HID; idx += 256) {
        int r = idx / HID, j = idx - r * HID;
        s_w1d[r][j] = W1[(160 + r) * HID + j];
    }
    __syncthreads();

    // Hoist all 18 B fragments of W2 into VGPRs.
    // B-frag layout (16x16x32): lane holds B[k=(lane>>4)*8+jj][n=lane&15]
    s16x8 bfr[6][3];
    for (int nt = 0; nt < 6; ++nt)
        for (int kt = 0; kt < 3; ++kt)
            bfr[nt][kt] = *(const s16x8*)&W2T[nt * 16 + m16][kt * 32 + q * 8];
    float b2v[6];
    for (int nt = 0; nt < 6; ++nt) b2v[nt] = b2[nt * 16 + m16];

    const bool i64 = (*flag64 != 0);
    const long long* ei64 = (const long long*)ei;

    for (int tile = blockIdx.x; tile < N_EDGESC / 64; tile += gridDim.x) {
        __syncthreads();  // protect s_*/hA from previous iteration readers

        if (t < 64) {
            int e = tile * 64 + t;
            int sN, dN;
            if (i64) { sN = (int)ei64[e]; dN = (int)ei64[N_EDGESC + e]; }
            else     { sN = ei[e];        dN = ei[N_EDGESC + e]; }
            s_src[t] = sN; s_dst[t] = dN;
            float ca, sa, cb, sb;
            __sincosf(2.0f * ori[dN], &sa, &ca);
            __sincosf(2.0f * ori[sN], &sb, &cb);
            s_c[t] = cb * ca + sb * sa;   // cos(2(beta-alpha))
            s_s[t] = sb * ca - cb * sa;   // sin(2(beta-alpha))
            float dx = pos[2 * sN] - pos[2 * dN];
            float dy = pos[2 * sN + 1] - pos[2 * dN + 1];
            float d2 = dx * dx + dy * dy;
            s_d[t] = sqrtf(d2) + 1e-6f;
            float c2f, s2f;
            if (d2 > 0.f) {
                float inv = 1.0f / d2;
                c2f = (dx * dx - dy * dy) * inv;  // cos(2phi)
                s2f = 2.0f * dx * dy * inv;       // sin(2phi)
            } else { c2f = 1.0f; s2f = 0.0f; }    // atan2(0,0)=0
            s_cg[t] = c2f * ca + s2f * sa;  // cos(2phi-2alpha)
            s_sg[t] = s2f * ca - c2f * sa;  // sin(2phi-2alpha)
        }
        __syncthreads();

        // Phase 1: build h = silu(pre1) for 64 edges x 96 units -> hA (bf16)
        for (int p = 0; p < 24; ++p) {
            int idx = p * 256 + t;       // < 6144
            int e = idx / HID;
            int j = idx - e * HID;
            int sN = s_src[e], dN = s_dst[e];
            float pre = bf2f(Pp[sN * HID + j]) + bf2f(Qt[dN * HID + j])
                      + s_c[e] * bf2f(Ut[sN * HID + j])
                      + s_s[e] * bf2f(Vt[sN * HID + j])
                      + s_d[e] * s_w1d[0][j] + s_cg[e] * s_w1d[1][j]
                      + s_sg[e] * s_w1d[2][j];
            float h = pre / (1.0f + __expf(-pre));  // silu
            hA[e][j] = f2bf(h);
        }
        __syncthreads();

        // Phase 2: wave w computes raw_msg for its 16 edges via MFMA
        // A-frag: lane holds A[m=lane&15][k=(lane>>4)*8+jj]
        f32x4 acc[6];
        for (int nt = 0; nt < 6; ++nt) acc[nt] = (f32x4){0.f, 0.f, 0.f, 0.f};
        s16x8 afr[3];
        for (int kt = 0; kt < 3; ++kt)
            afr[kt] = *(const s16x8*)&hA[w * 16 + m16][kt * 32 + q * 8];
        for (int nt = 0; nt < 6; ++nt)
            for (int kt = 0; kt < 3; ++kt)
                acc[nt] = __builtin_amdgcn_mfma_f32_16x16x32_bf16(
                    afr[kt], bfr[nt][kt], acc[nt], 0, 0, 0);

        // Phase 3: epilogue + scatter. C/D: col=lane&15, row=(lane>>4)*4+reg
        for (int nt = 0; nt < 6; ++nt) {
            int u = nt * 16 + m16;
            for (int r = 0; r < 4; ++r) {
                int eloc = w * 16 + q * 4 + r;
                int dN = s_dst[eloc];
                float val = acc[nt][r] + b2v[nt];
                if (u < SDIM) atomicAdd(&out[dN * SDIM + u], val);
                else atomicAdd(&out[N_NODESC * SDIM + dN * VDIM + (u - SDIM)], val);
            }
        }
    }
}

// ---------------------------------------------------------------------------
// Fallback (used only if ws too small for tables): fully per-edge, correct but slow.
__global__ __launch_bounds__(192) void edge_fallback(
    const int* __restrict__ ei, const float* __restrict__ hs,
    const float* __restrict__ hv, const float* __restrict__ pos,
    const float* __restrict__ ori, const float* __restrict__ W1,
    const float* __restrict__ b1, const float* __restrict__ W2,
    const float* __restrict__ b2, const int* __restrict__ flag64,
    float* __restrict__ out) {
    __shared__ float s_msg[IN_DIMC];
    __shared__ float s_h[HID];
    int e = blockIdx.x;
    int t = threadIdx.x;
    const bool i64 = (*flag64 != 0);
    int sN, dN;
    if (i64) {
        const long long* e64 = (const long long*)ei;
        sN = (int)e64[e]; dN = (int)e64[N_EDGESC + e];
    } else { sN = ei[e]; dN = ei[N_EDGESC + e]; }

    if (t < IN_DIMC) {
        if (t < 64) s_msg[t] = hs[sN * SDIM + t];
        else if (t < 128) s_msg[t] = hs[dN * SDIM + (t - 64)];
        else {
            float ca, sa, cb, sb;
            __sincosf(2.0f * ori[dN], &sa, &ca);
            __sincosf(2.0f * ori[sN], &sb, &cb);
            float c = cb * ca + sb * sa;
            float s = sb * ca - cb * sa;
            float dx = pos[2 * sN] - pos[2 * dN];
            float dy = pos[2 * sN + 1] - pos[2 * dN + 1];
            float d2 = dx * dx + dy * dy;
            if (t < 160) {
                int pr = (t - 128) >> 1;
                float x = hv[sN * VDIM + 2 * pr], y = hv[sN * VDIM + 2 * pr + 1];
                s_msg[t] = ((t & 1) == 0) ? (c * x - s * y) : (s * x + c * y);
            } else if (t == 160) s_msg[t] = sqrtf(d2) + 1e-6f;
            else {
                float c2f = 1.0f, s2f = 0.0f;
                if (d2 > 0.f) {
                    float inv = 1.0f / d2;
                    c2f = (dx * dx - dy * dy) * inv;
                    s2f = 2.0f * dx * dy * inv;
                }
                s_msg[t] = (t == 161) ? (c2f * ca + s2f * sa) : (s2f * ca - c2f * sa);
            }
        }
    }
    __syncthreads();
    if (t < HID) {
        float a = b1[t];
        for (int k = 0; k < IN_DIMC; ++k) a += s_msg[k] * W1[k * HID + t];
        s_h[t] = a / (1.0f + __expf(-a));
    }
    __syncthreads();
    if (t < HID) {
        float a = b2[t];
        for (int k = 0; k < HID; ++k) a += s_h[k] * W2[k * HID + t];
        if (t < SDIM) atomicAdd(&out[dN * SDIM + t], a);
        else atomicAdd(&out[N_NODESC * SDIM + dN * VDIM + (t - SDIM)], a);
    }
}

// ---------------------------------------------------------------------------
extern "C" void kernel_launch(void* const* d_in, const int* in_sizes, int n_in,
                              void* d_out, int out_size, void* d_ws, size_t ws_size,
                              hipStream_t stream) {
    const float* hs  = (const float*)d_in[0];
    const float* hv  = (const float*)d_in[1];
    const int*   ei  = (const int*)d_in[2];
    const float* pos = (const float*)d_in[3];
    const float* ori = (const float*)d_in[4];
    const float* W1  = (const float*)d_in[5];
    const float* b1  = (const float*)d_in[6];
    const float* W2  = (const float*)d_in[7];
    const float* b2  = (const float*)d_in[8];
    float* out = (float*)d_out;

    const size_t TBL = (size_t)N_NODESC * HID * sizeof(__hip_bfloat16);  // 9.6 MB
    const bool big = ws_size >= 4 * TBL + 16;

    init_out<<<(N_NODESC * (SDIM + VDIM) + 255) / 256, 256, 0, stream>>>(hs, hv, out);

    if (big) {
        char* ws = (char*)d_ws;
        __hip_bfloat16* Pp = (__hip_bfloat16*)(ws);
        __hip_bfloat16* Qt = (__hip_bfloat16*)(ws + TBL);
        __hip_bfloat16* Ut = (__hip_bfloat16*)(ws + 2 * TBL);
        __hip_bfloat16* Vt = (__hip_bfloat16*)(ws + 3 * TBL);
        int* flag = (int*)(ws + 4 * TBL);
        detect_kernel<<<1, 64, 0, stream>>>(ei, flag);
        node_precompute<<<N_NODESC, 128, 0, stream>>>(hs, hv, W1, b1, Pp, Qt, Ut, Vt);
        edge_kernel<<<2500, 256, 0, stream>>>(ei, pos, ori, W1, W2, b2,
                                              Pp, Qt, Ut, Vt, flag, out);
    } else {
        int* flag = (int*)d_ws;
        detect_kernel<<<1, 64, 0, stream>>>(ei, flag);
        edge_fallback<<<N_EDGESC, 192, 0, stream>>>(ei, hs, hv, pos, ori, W1, b1,
                                                    W2, b2, flag, out);
    }
}